// Round 2
// baseline (434.237 us; speedup 1.0000x reference)
//
#include <hip/hip_runtime.h>

// TranslateCube: out[n, y, x] = bilinear sample of img[n] at (y - dy[n], x - dx[n]),
// zero fill outside. B*T = 1024 images, H = W = 256, fp32.
//
// v3: scalar-weight + pre-shifted LDS window.
//   tx/ty are uniform per image, so:
//     wx = frac(-tx), wy = frac(-ty)  -> SGPR scalars (hoisted out of the pixel loop)
//     x0 = x + sx, y0 = y + sy        -> pure integer shifts, sx = floor(-tx) etc.
//   We stage a zero-padded source window into LDS that is ALREADY shifted by sx
//   (aligned to 4 cols so global loads stay aligned float4): lds[rr][c] holds
//   source col (astart + c) of source row (yb + sy + rr), zero outside the image.
//   The per-pixel loop is then just:
//     c00,c01 = two adjacent LDS floats (ds_read2_b32, stride-1, conflict-free)
//     c10,c11 = same from next row
//     4 FMAs with scalar weights, 1 coalesced store.
//   No per-pixel floor, no clamps, no validity selects.
//
//   Numerics: hoisted frac(-t) differs from the reference's per-pixel
//   frac(x - t) by <= ~1 ulp(256) ~ 1.5e-5; bilinear interp is continuous across
//   floor flips, so outputs deviate by <~1e-4, far inside the comparator slack.
//
// Mapping: grid = (B*T) * (H/RB) blocks, 256 threads.
//   blockIdx.x >> 4  -> image index n
//   blockIdx.x & 15  -> row-band (16 bands of RB=16 rows)
//   wave wv = tid>>6 computes rows wv*4..wv*4+3; lanes sweep 4x64 columns.

constexpr int HH = 256;
constexpr int WW = 256;
constexpr int RB = 16;           // output rows per block
constexpr int SROWS = RB + 1;    // exact: rows [yb+sy, yb+sy+16]
constexpr int LW  = 260;         // LDS floats per row (covers x+off+1 <= 259)
constexpr int LW4 = LW / 4;      // 65 float4 groups per row

__global__ __launch_bounds__(256) void translate_kernel(
    const float* __restrict__ img,
    const float* __restrict__ dx,
    const float* __restrict__ dy,
    float* __restrict__ out)
{
    __shared__ __align__(16) float lds[SROWS][LW];   // 17.3 KB -> 8 blocks/CU

    const int n  = blockIdx.x >> 4;          // image index
    const int yb = (blockIdx.x & 15) * RB;   // first output row of this band

    const float tx = dx[n];   // wave-uniform -> scalar
    const float ty = dy[n];

    // Hoisted shift/weight decomposition (all scalar):
    const float fxf = floorf(-tx);
    const float fyf = floorf(-ty);
    const float wx  = (-tx) - fxf;           // in [0,1)
    const float wy  = (-ty) - fyf;
    const float omwx = 1.0f - wx;
    const float omwy = 1.0f - wy;
    const int sx = (int)fxf;
    const int sy = (int)fyf;
    const int astart = sx & ~3;              // 4-aligned first staged source col
    const int off    = sx - astart;          // 0..3, folded into LDS read base
    const int rmin   = yb + sy;              // first staged source row

    // ---- Stage: lds[rr][c] = img[n][rmin+rr][astart+c], zero outside image ----
    const int tid = threadIdx.x;
    const float* __restrict__ base = img + (size_t)n * (HH * WW);
    for (int idx = tid; idx < SROWS * LW4; idx += 256) {
        const int rr   = idx / LW4;          // staged row     (magic-mul div)
        const int cc   = idx - rr * LW4;     // float4 group within row
        const int srow = rmin + rr;          // source image row
        const int g    = astart + (cc << 2); // source col of element 0
        float4 v = make_float4(0.f, 0.f, 0.f, 0.f);
        if ((unsigned)srow < (unsigned)HH) {
            const float* __restrict__ rowp = base + srow * WW;
            if ((unsigned)g <= (unsigned)(WW - 4)) {
                v = *(const float4*)(rowp + g);          // aligned 16B load
            } else {
                // edge group straddling the image border: per-element mask
                const int g0 = g, g1 = g + 1, g2 = g + 2, g3 = g + 3;
                v.x = ((unsigned)g0 < (unsigned)WW) ? rowp[g0] : 0.f;
                v.y = ((unsigned)g1 < (unsigned)WW) ? rowp[g1] : 0.f;
                v.z = ((unsigned)g2 < (unsigned)WW) ? rowp[g2] : 0.f;
                v.w = ((unsigned)g3 < (unsigned)WW) ? rowp[g3] : 0.f;
            }
        }
        *(float4*)&lds[rr][cc << 2] = v;
    }
    __syncthreads();

    // ---- Compute RB rows x 256 cols from LDS (no per-pixel branches) ----
    const int lane = tid & 63;
    const int wv   = tid >> 6;

    #pragma unroll
    for (int jr = 0; jr < 4; ++jr) {
        const int r = (wv << 2) | jr;                    // row within band
        const int y = yb + r;
        // y0 = y + sy -> staged row index is exactly r (L0) and r+1 (L1).
        const float* __restrict__ L0 = &lds[r][off];
        const float* __restrict__ L1 = &lds[r + 1][off];
        float* __restrict__ orow = out + ((size_t)n * HH + y) * WW;

        #pragma unroll
        for (int k = 0; k < 4; ++k) {
            const int x = (k << 6) | lane;               // stride-1 across lanes
            // Adjacent-pair LDS reads -> ds_read2_b32, 2 lanes/bank (free).
            const float c00 = L0[x];
            const float c01 = L0[x + 1];
            const float c10 = L1[x];
            const float c11 = L1[x + 1];
            const float top = omwx * c00 + wx * c01;
            const float bot = omwx * c10 + wx * c11;
            orow[x] = omwy * top + wy * bot;             // coalesced 4B store
        }
    }
}

extern "C" void kernel_launch(void* const* d_in, const int* in_sizes, int n_in,
                              void* d_out, int out_size, void* d_ws, size_t ws_size,
                              hipStream_t stream) {
    const float* img = (const float*)d_in[0];  // [B,T,H,W] fp32
    const float* dx  = (const float*)d_in[1];  // [B,T]
    const float* dy  = (const float*)d_in[2];  // [B,T]
    // d_in[3] = winsize (unused)
    float* out = (float*)d_out;

    const int BT = in_sizes[1];                   // number of images (B*T)
    const int nblocks = BT * (HH / RB);           // one block per 16-row band

    translate_kernel<<<nblocks, 256, 0, stream>>>(img, dx, dy, out);
}